// Round 7
// baseline (352.696 us; speedup 1.0000x reference)
//
#include <hip/hip_runtime.h>
#include <hip/hip_bf16.h>
#include <stdint.h>

typedef __attribute__((ext_vector_type(8))) __bf16 bf16x8;
typedef __attribute__((ext_vector_type(4))) float f32x4;

#define KP 4160   // padded K: 4096 (quantized x) + 32 (lora T) + 32 (zero pad)

__device__ inline void async_copy16(const void* g, void* l) {
  __builtin_amdgcn_global_load_lds((const __attribute__((address_space(1))) void*)g,
                                   (__attribute__((address_space(3))) void*)l, 16, 0, 0);
}

// ---------------------------------------------------------------------------
// Kernel 1 (FUSED, verified r5/r6): per-block window = rows [16*bx,16*bx+16)
// x cols [1024*by,1024*by+1024).  Part A: SmoothQuant + NVFP4 fake-quant ->
// bf16 into A_big (exact reference fp32 math).  Part B: LoRA partial T via
// MFMA 16x16x32 -> fp32 partial Tp[by][4096][32] (Tp lives in d_out, dead
// until gemm overwrites it).
// ---------------------------------------------------------------------------
__global__ __launch_bounds__(256) void fused_quant_lora_kernel(
    const float* __restrict__ x, const float* __restrict__ ss,
    const float* __restrict__ la, __bf16* __restrict__ Ab,
    float* __restrict__ Tp) {
  __shared__ float red[4][16][32];
  int tid  = threadIdx.x;
  int m0   = blockIdx.x << 4;                 // 16-row strip
  int by   = blockIdx.y;                      // 1024-col k-chunk

  // ---- Part A: quant.  thread t -> row m0+(t>>4), col-blocks (t&15)+16i ----
  {
    int row = m0 + (tid >> 4);
    int cb0 = tid & 15;
#pragma unroll
    for (int i = 0; i < 4; i++) {
      int col = (by << 10) + ((cb0 + (i << 4)) << 4);
      const float4* xp = (const float4*)(x + ((size_t)row << 12) + col);
      const float4* sp = (const float4*)(ss + col);
      float xs[16];
#pragma unroll
      for (int j = 0; j < 4; j++) {
        float4 xv = xp[j]; float4 sv = sp[j];
        xs[4*j+0] = xv.x * sv.x; xs[4*j+1] = xv.y * sv.y;
        xs[4*j+2] = xv.z * sv.z; xs[4*j+3] = xv.w * sv.w;
      }
      float amax = 0.f;
#pragma unroll
      for (int j = 0; j < 16; j++) amax = fmaxf(amax, fabsf(xs[j]));
      amax = fmaxf(amax, 1e-12f);
      float scale = amax / 6.0f;              // IEEE fp32 divide, same as np
      bf16x8 o0, o1;
#pragma unroll
      for (int j = 0; j < 16; j++) {
        float a  = fabsf(xs[j]);
        float xn = a / scale;                 // IEEE fp32 divide, same as np
        float bestd = xn;                     // |xn - 0.0|
        float lvl   = 0.f;
        const float L[7] = {0.5f, 1.f, 1.5f, 2.f, 3.f, 4.f, 6.f};
#pragma unroll
        for (int l = 0; l < 7; l++) {         // strict < = first-on-tie (np)
          float d = fabsf(xn - L[l]);
          if (d < bestd) { bestd = d; lvl = L[l]; }
        }
        float mag = lvl * scale;
        float q = (xs[j] > 0.f) ? mag : ((xs[j] < 0.f) ? -mag : 0.f);
        if (j < 8) o0[j] = (__bf16)q; else o1[j-8] = (__bf16)q;
      }
      __bf16* dst = Ab + (size_t)row * KP + col;
      *(bf16x8*)dst = o0;
      *(bf16x8*)(dst + 8) = o1;
    }
  }

  // ---- Part B: LoRA partial via MFMA (verified fragment layout) ----
  {
    int wave = tid >> 6, lane = tid & 63;
    int lrow = lane & 15, kg = lane >> 4;
    int kbase = (by << 10) + (wave << 8);     // 256-wide window per wave
    f32x4 acc0 = {0.f,0.f,0.f,0.f}, acc1 = {0.f,0.f,0.f,0.f};
    const float* xrow = x + ((size_t)(m0 + lrow) << 12);
    const float* a0   = la + ((size_t)lrow << 12);
    const float* a1   = a0 + (16 << 12);
#pragma unroll
    for (int k0 = 0; k0 < 256; k0 += 32) {
      int kk = kbase + k0 + (kg << 3);
      float xv[8], sv[8], v0[8], v1[8];
      *(float4*)&xv[0] = *(const float4*)(xrow + kk);
      *(float4*)&xv[4] = *(const float4*)(xrow + kk + 4);
      *(float4*)&sv[0] = *(const float4*)(ss + kk);
      *(float4*)&sv[4] = *(const float4*)(ss + kk + 4);
      *(float4*)&v0[0] = *(const float4*)(a0 + kk);
      *(float4*)&v0[4] = *(const float4*)(a0 + kk + 4);
      *(float4*)&v1[0] = *(const float4*)(a1 + kk);
      *(float4*)&v1[4] = *(const float4*)(a1 + kk + 4);
      bf16x8 af, b0, b1;
#pragma unroll
      for (int j = 0; j < 8; j++) {
        af[j] = (__bf16)(xv[j] * sv[j]);
        b0[j] = (__bf16)v0[j];
        b1[j] = (__bf16)v1[j];
      }
      acc0 = __builtin_amdgcn_mfma_f32_16x16x32_bf16(af, b0, acc0, 0, 0, 0);
      acc1 = __builtin_amdgcn_mfma_f32_16x16x32_bf16(af, b1, acc1, 0, 0, 0);
    }
#pragma unroll
    for (int r = 0; r < 4; r++) {
      red[wave][kg*4 + r][lrow]      = acc0[r];   // verified layout (r1-r6)
      red[wave][kg*4 + r][16 + lrow] = acc1[r];
    }
    __syncthreads();
    for (int o = tid; o < 512; o += 256) {
      int rr = o >> 5, cc = o & 31;
      float s = red[0][rr][cc] + red[1][rr][cc] + red[2][rr][cc] + red[3][rr][cc];
      Tp[((size_t)by * 4096 + m0 + rr) * 32 + cc] = s;
    }
  }
}

// ---------------------------------------------------------------------------
// Kernel 2 (MERGED wconv + lora_fix, verified r6): blocks [0,8320) convert
// w -> bf16 into B_big cols 0:4096, lora_b -> 4096:4128, zeros -> 4128:4160.
// Blocks [8320,8832) sum the 4 Tp partials -> bf16 T into A_big[:,4096:4128]
// + zero pad.  Tp lives in d_out, so no aliasing hazard with Bb writes.
// ---------------------------------------------------------------------------
__global__ __launch_bounds__(256) void wconv_fix_kernel(const float* __restrict__ w,
                                                        const float* __restrict__ lb,
                                                        const float* __restrict__ Tp,
                                                        __bf16* __restrict__ Bb,
                                                        __bf16* __restrict__ Ab) {
  int b = blockIdx.x;
  if (b < 8320) {
    int id  = b * 256 + threadIdx.x;          // < 4096*520
    int row = id / 520;
    int g   = id - row * 520;
    bf16x8 v;
    if (g < 512) {
      const float4* wp = (const float4*)(w + ((size_t)row << 12) + (g << 3));
      float4 a = wp[0], bb = wp[1];
      v[0]=(__bf16)a.x;  v[1]=(__bf16)a.y;  v[2]=(__bf16)a.z;  v[3]=(__bf16)a.w;
      v[4]=(__bf16)bb.x; v[5]=(__bf16)bb.y; v[6]=(__bf16)bb.z; v[7]=(__bf16)bb.w;
    } else if (g < 516) {
      const float* p = lb + (size_t)row * 32 + ((g - 512) << 3);
#pragma unroll
      for (int j = 0; j < 8; j++) v[j] = (__bf16)p[j];
    } else {
#pragma unroll
      for (int j = 0; j < 8; j++) v[j] = (__bf16)0.f;
    }
    *(bf16x8*)(Bb + (size_t)row * KP + ((size_t)g << 3)) = v;
  } else {
    int id  = (b - 8320) * 256 + threadIdx.x; // < 4096*32
    int row = id >> 5, cc = id & 31;
    float s = 0.f;
#pragma unroll
    for (int kc = 0; kc < 4; kc++)
      s += Tp[((size_t)kc * 4096 + row) * 32 + cc];
    __bf16* dst = Ab + (size_t)row * KP + 4096;
    dst[cc]      = (__bf16)s;
    dst[32 + cc] = (__bf16)0.f;
  }
}

// ---------------------------------------------------------------------------
// Kernel 3: C[4096,4096] = A_big @ B_big^T + bias.  REVERTED to the r5
// 16x16x32 version: verified 0 LDS bank conflicts / ~173.5 us / MfmaUtil 35%.
// r6's 32x32x16 variant hit structural 4-way LDS conflicts (1.7e7 extra
// cycles ~ 28 us): with m=lane&31, 4 lanes share each 3-bit row-XOR value,
// and the global_load_lds-constrained layout only has a 3-bit swizzle budget
// (8 k-quads per 128 B row).  16x16 frags keep that aliasing at 2-way = free.
// ---------------------------------------------------------------------------
__global__ __launch_bounds__(256) void gemm_kernel(const __bf16* __restrict__ A,
                                                   const __bf16* __restrict__ B,
                                                   const float* __restrict__ bias,
                                                   float* __restrict__ C) {
  __shared__ __bf16 As[128 * 64];
  __shared__ __bf16 Bs[128 * 64];
  int tid  = threadIdx.x;
  int wave = tid >> 6, lane = tid & 63;
  int bm = blockIdx.x >> 5, bn = blockIdx.x & 31;
  size_t m0 = (size_t)bm << 7, n0 = (size_t)bn << 7;
  int wm = wave >> 1, wn = wave & 1;
  int lrow = lane & 15, kg = lane >> 4;
  int srow = lane >> 3;                       // row within 8-row staging chunk
  int sk   = ((lane & 7) ^ srow) << 3;        // swizzled k element offset
  f32x4 acc[4][4];
#pragma unroll
  for (int r = 0; r < 4; r++)
#pragma unroll
    for (int c = 0; c < 4; c++) acc[r][c] = (f32x4){0.f,0.f,0.f,0.f};

  for (int k = 0; k < KP; k += 64) {
#pragma unroll
    for (int i = 0; i < 4; i++) {
      int chunk = (wave << 2) + i;            // 16 chunks of 8 rows x 64 k
      int row   = (chunk << 3) + srow;
      async_copy16(A + (m0 + row) * (size_t)KP + k + sk, (void*)(As + chunk * 512));
      async_copy16(B + (n0 + row) * (size_t)KP + k + sk, (void*)(Bs + chunk * 512));
    }
    __syncthreads();
#pragma unroll
    for (int ks = 0; ks < 2; ks++) {
      bf16x8 af[4], bfr[4];
      int kx = ((ks << 6) + (kg << 4)) ^ ((lrow & 7) << 4);
#pragma unroll
      for (int r = 0; r < 4; r++) {
        int ml = (wm << 6) + (r << 4) + lrow;
        af[r]  = *(const bf16x8*)((const char*)As + ml * 128 + kx);
        int nl = (wn << 6) + (r << 4) + lrow;
        bfr[r] = *(const bf16x8*)((const char*)Bs + nl * 128 + kx);
      }
#pragma unroll
      for (int r = 0; r < 4; r++)
#pragma unroll
        for (int c = 0; c < 4; c++)
          acc[r][c] = __builtin_amdgcn_mfma_f32_16x16x32_bf16(af[r], bfr[c], acc[r][c], 0, 0, 0);
    }
    __syncthreads();
  }
  // epilogue: + bias, fp32 store. C frag layout: col=lane&15, row=kg*4+reg.
#pragma unroll
  for (int c = 0; c < 4; c++) {
    int col = (int)n0 + (wn << 6) + (c << 4) + lrow;
    float bv = bias[col];
#pragma unroll
    for (int r = 0; r < 4; r++) {
      size_t rowb = m0 + (wm << 6) + (r << 4) + (kg << 2);
#pragma unroll
      for (int q = 0; q < 4; q++)
        C[(rowb + q) * 4096 + col] = acc[r][c][q] + bv;
    }
  }
}

extern "C" void kernel_launch(void* const* d_in, const int* in_sizes, int n_in,
                              void* d_out, int out_size, void* d_ws, size_t ws_size,
                              hipStream_t stream) {
  const float* x    = (const float*)d_in[0];   // [2,2048,4096]
  const float* ss   = (const float*)d_in[1];   // [4096]
  const float* w    = (const float*)d_in[2];   // [4096,4096]
  const float* la   = (const float*)d_in[3];   // [32,4096]
  const float* lb   = (const float*)d_in[4];   // [4096,32]
  const float* bias = (const float*)d_in[5];   // [4096]
  float* out = (float*)d_out;                  // [2,2048,4096] fp32

  __bf16* Ab = (__bf16*)d_ws;                  // [4096, 4160] bf16  (34.1 MB)
  __bf16* Bb = Ab + (size_t)4096 * KP;         // [4096, 4160] bf16  (34.1 MB)
  // Tp lives in d_out scratch space: 4*4096*32*4 = 2 MB << 67 MB.  Consumed
  // by wconv_fix, then d_out is fully overwritten by gemm.
  float* Tp = out;                             // [4][4096][32] fp32 (2 MB)

  fused_quant_lora_kernel<<<dim3(256, 4), 256, 0, stream>>>(x, ss, la, Ab, Tp);
  wconv_fix_kernel<<<8832, 256, 0, stream>>>(w, lb, Tp, Bb, Ab);
  gemm_kernel<<<1024, 256, 0, stream>>>(Ab, Bb, bias, out);
}